// Round 6
// baseline (113.744 us; speedup 1.0000x reference)
//
#include <hip/hip_runtime.h>

typedef float v2f __attribute__((ext_vector_type(2)));
typedef float v4f __attribute__((ext_vector_type(4)));

#define TPB    256
#define XPT    16                 // x points per thread
#define XPK    (XPT / 2)          // 8 packed x-pairs
#define XTILE  (TPB * XPT)        // 4096 x per block
#define NPTS   8192
#define GX     (NPTS / XTILE)     // 2
#define GY     64                 // y chunks
#define YTILE  (NPTS / GY)        // 128 y per block, one LDS stage
#define NB     4
#define TOTPTS (NB * NPTS)        // 32768
#define NSLICE (2 * NB)           // 8 (dir,batch) slices
#define WS2_FLOATS ((size_t)GY * NSLICE * NPTS)   // 4,194,304 floats = 16 MB
#define NPARTIAL ((2 * TOTPTS) / 64)              // 1024 per-wave partials

// ---------------------------------------------------------------------------
// R5 lessons: (1) __builtin_elementwise_fma on v2f did NOT yield v_pk_fma_f32
// (VALU busy-time == scalar ideal) -> force VOP3P via inline asm, with op_sel
// broadcasts so y-components need ZERO splat movs. (2) 4.19M end-of-block
// atomicMin RMWs drained ~18us with nothing to overlap (uniform block work)
// -> disjoint-slice plain stores (drain ~1us) + finalize chunk-reduce.
// Fixed ~50us harness overhead is dispatch-count-independent (R4).
// ---------------------------------------------------------------------------

// t_pair = hy - x.y for 2 x-points against one y, entirely in packed ops:
//   fma1: acc = nx * <y.x,y.x> + <y.w,y.w>   (src1 lo-bcast, src2 hi-bcast)
//   fma2: acc = ny * <y.y,y.y> + acc         (src1 hi-bcast)
//   fma3: acc = nz * <y.z,y.z> + acc         (src1 lo-bcast)
__device__ __forceinline__ v2f pk_t(v2f nx, v2f ny, v2f nz, v2f yxy, v2f yzw) {
    v2f acc;
    asm("v_pk_fma_f32 %0, %1, %2, %3 op_sel:[0,0,1] op_sel_hi:[1,0,1]"
        : "=v"(acc) : "v"(nx), "v"(yxy), "v"(yzw));
    asm("v_pk_fma_f32 %0, %1, %2, %0 op_sel:[0,1,0] op_sel_hi:[1,1,1]"
        : "+v"(acc) : "v"(ny), "v"(yxy));
    asm("v_pk_fma_f32 %0, %1, %2, %0 op_sel:[0,0,0] op_sel_hi:[1,0,1]"
        : "+v"(acc) : "v"(nz), "v"(yzw));
    return acc;
}

// grid = (GX, GY, 2*NB) = (2, 64, 8) = 1024 blocks. blockIdx.z = dir*4 + b.
// CHUNKED=1: plain stores to disjoint (chunk, z) slices (no init, no atomics)
// CHUNKED=0: flip-key u32 atomicMin fallback (needs 0xFF memset)
template <int CHUNKED>
__global__ void __launch_bounds__(TPB) nnmin_pk(
        const float* __restrict__ T, const float* __restrict__ P,
        float* __restrict__ ws2, unsigned* __restrict__ keys)
{
    __shared__ v4f sY[YTILE];      // (yx, yy, yz, 0.5*|y|^2), 2 KB

    const int z   = blockIdx.z;
    const int dir = z >> 2;
    const int b   = z & 3;
    const float* Xb = (dir ? P : T) + (size_t)b * NPTS * 3;
    const float* Yb = (dir ? T : P) + (size_t)b * NPTS * 3;
    const int t  = threadIdx.x;
    const int x0 = blockIdx.x * XTILE;
    const int y0 = blockIdx.y * YTILE;

    if (t < YTILE) {   // stage Y tile with precomputed hy = 0.5*|y|^2
        const float* yp = Yb + (size_t)(y0 + t) * 3;
        float yx = yp[0], yy = yp[1], yz = yp[2];
        sY[t] = (v4f){yx, yy, yz, 0.5f * (yx * yx + yy * yy + yz * yz)};
    }

    // x packed in pairs, pre-negated (fold of the subtraction)
    v2f nxx[XPK], nxy[XPK], nxz[XPK], m2[XPK];
#pragma unroll
    for (int k = 0; k < XPK; ++k) {
        const float* xp0 = Xb + (size_t)(x0 + (2 * k + 0) * TPB + t) * 3;
        const float* xp1 = Xb + (size_t)(x0 + (2 * k + 1) * TPB + t) * 3;
        nxx[k] = (v2f){-xp0[0], -xp1[0]};
        nxy[k] = (v2f){-xp0[1], -xp1[1]};
        nxz[k] = (v2f){-xp0[2], -xp1[2]};
        m2[k]  = (v2f){3.0e38f, 3.0e38f};
    }
    __syncthreads();

    // 5 issue slots per 2 pairs, zero movs: 3 pk_fma(op_sel) + 2 v_min
#pragma unroll 4
    for (int j = 0; j < YTILE; ++j) {
        v4f Y = sY[j];
        v2f yxy = {Y.x, Y.y}, yzw = {Y.z, Y.w};
#pragma unroll
        for (int k = 0; k < XPK; ++k) {
            v2f acc = pk_t(nxx[k], nxy[k], nxz[k], yxy, yzw);
            m2[k] = __builtin_elementwise_min(m2[k], acc);
        }
    }

    if (CHUNKED) {
        // disjoint slice per (chunk, z): plain coalesced stores
        float* o = ws2 + ((size_t)blockIdx.y * NSLICE + z) * NPTS + x0 + t;
#pragma unroll
        for (int k = 0; k < XPK; ++k) {
            o[(2 * k + 0) * TPB] = m2[k].x;
            o[(2 * k + 1) * TPB] = m2[k].y;
        }
    } else {
        unsigned* o = keys + (size_t)dir * TOTPTS + (size_t)b * NPTS + x0 + t;
#pragma unroll
        for (int k = 0; k < XPK; ++k) {
            unsigned b0 = __float_as_uint(m2[k].x);
            unsigned b1 = __float_as_uint(m2[k].y);
            atomicMin(&o[(2 * k + 0) * TPB],
                      b0 ^ ((b0 & 0x80000000u) ? 0xFFFFFFFFu : 0x80000000u));
            atomicMin(&o[(2 * k + 1) * TPB],
                      b1 ^ ((b1 & 0x80000000u) ? 0xFFFFFFFFu : 0x80000000u));
        }
    }
}

// Reduce chunks (or decode key), add hx, sqrt; mins_seeds; per-wave sums.
template <int CHUNKED>
__global__ void __launch_bounds__(TPB) finalize_kernel(
        const float* __restrict__ ws2, const unsigned* __restrict__ keys,
        const float* __restrict__ T, const float* __restrict__ P,
        float* __restrict__ out, float* __restrict__ partials)
{
    int i   = blockIdx.x * TPB + threadIdx.x;   // 0 .. 2*TOTPTS-1
    int dir = (i >= TOTPTS) ? 1 : 0;            // uniform per block
    int idx = i - dir * TOTPTS;
    int b   = idx >> 13;
    int x   = idx & (NPTS - 1);
    int z   = dir * 4 + b;

    float m;
    if (CHUNKED) {
        m = 3.0e38f;
        const float* p = ws2 + (size_t)z * NPTS + x;   // slice (c*8+z), off x
#pragma unroll 8
        for (int c = 0; c < GY; ++c)
            m = fminf(m, p[(size_t)c * NSLICE * NPTS]);
    } else {
        unsigned k  = keys[i];
        unsigned bb = (k & 0x80000000u) ? (k ^ 0x80000000u) : ~k;
        m = __uint_as_float(bb);
    }

    const float* xp = (dir ? P : T) + ((size_t)b * NPTS + x) * 3;
    float a0 = xp[0], a1 = xp[1], a2 = xp[2];
    float hx = 0.5f * (a0 * a0 + a1 * a1 + a2 * a2);
    float d  = sqrtf(fmaxf(2.0f * (hx + m), 0.0f));
    if (dir) out[1 + idx] = d;                  // mins_seeds

#pragma unroll
    for (int off = 32; off > 0; off >>= 1)
        d += __shfl_down(d, off, 64);
    if ((threadIdx.x & 63) == 0) partials[i >> 6] = d;
}

__global__ void scalar_kernel(const float* __restrict__ partials,
                              float* __restrict__ out) {
    int t = threadIdx.x;                        // 64 threads
    float s = 0.0f;
#pragma unroll
    for (int k = 0; k < NPARTIAL / 64; ++k)
        s += partials[t * (NPARTIAL / 64) + k];
#pragma unroll
    for (int off = 32; off > 0; off >>= 1)
        s += __shfl_down(s, off, 64);
    if (t == 0) out[0] = s * (1.0f / (float)TOTPTS);
}

extern "C" void kernel_launch(void* const* d_in, const int* in_sizes, int n_in,
                              void* d_out, int out_size, void* d_ws, size_t ws_size,
                              hipStream_t stream) {
    const float* truep = (const float*)d_in[0];   // [4, 8192, 3] fp32
    const float* predp = (const float*)d_in[1];   // [4, 8192, 3] fp32
    float* out = (float*)d_out;                   // [1 + 32768] fp32

    dim3 grid(GX, GY, 2 * NB);                    // (2, 64, 8) = 1024 blocks
    const size_t need = (WS2_FLOATS + NPARTIAL) * 4;

    if (ws_size >= need) {                        // branch constant per-run
        float* ws2      = (float*)d_ws;
        float* partials = ws2 + WS2_FLOATS;
        nnmin_pk<1><<<grid, TPB, 0, stream>>>(truep, predp, ws2, nullptr);
        finalize_kernel<1><<<(2 * TOTPTS) / TPB, TPB, 0, stream>>>(
            ws2, nullptr, truep, predp, out, partials);
        scalar_kernel<<<1, 64, 0, stream>>>(partials, out);
    } else {
        unsigned* keys     = (unsigned*)d_ws;
        float*    partials = (float*)(keys + 2 * TOTPTS);
        hipMemsetAsync(keys, 0xFF, (size_t)2 * TOTPTS * 4, stream);
        nnmin_pk<0><<<grid, TPB, 0, stream>>>(truep, predp, nullptr, keys);
        finalize_kernel<0><<<(2 * TOTPTS) / TPB, TPB, 0, stream>>>(
            nullptr, keys, truep, predp, out, partials);
        scalar_kernel<<<1, 64, 0, stream>>>(partials, out);
    }
}

// Round 7
// 94.761 us; speedup vs baseline: 1.2003x; 1.2003x over previous
//
#include <hip/hip_runtime.h>

typedef __attribute__((ext_vector_type(8)))  short bf16x8;   // 8 bf16 = 4 VGPRs
typedef __attribute__((ext_vector_type(16))) float f32x16;   // MFMA 32x32 C/D
typedef __attribute__((ext_vector_type(4)))  float v4f;

#define TPB    256
#define NPTS   8192
#define NB     4
#define TOTPTS (NB * NPTS)        // 32768
#define XBLK   256                // x per block (64 per wave: 2 B-frags)
#define YTILE  512                // y per block
#define NTILES (YTILE / 32)       // 16 MFMA tiles
#define GXB    (NPTS / XBLK)      // 32
#define GYB    (NPTS / YTILE)     // 16
#define NPARTIAL ((2 * TOTPTS) / 64)

// ---------------------------------------------------------------------------
// R6 lessons: fp32 VALU is AT its floor (busy 28.7us == 27.3us ideal in
// R4/R5/R6; v_pk_fma_f32 gives no throughput — 157 TF spec includes packing).
// -> move the dot product to the matrix pipe. t' = hy - x.y as ONE
// mfma_f32_32x32x16_bf16 with compensated bf16 hi/lo split over 11 K-slots:
//   A (y, M-side) k: [yh0,yl0,yh0, yh1,yl1,yh1, yh2,yl2,yh2, hyh,hyl]
//   B (x, N-side) k: [-xh0,-xh0,-xl0, ..., -xh2,-xh2, -xl2, 1, 1]
// dot = hy - (xh.yh + xh.yl + xl.yh)  (missing xl.yl ~ 2e-4 in d^2).
// Cross-chunk combine: R5's flip-key atomicMin (atomics measured ~free;
// 16MB chunk-ws regressed finalize). Fixed ~50us harness overhead regardless.
// ---------------------------------------------------------------------------

__device__ __forceinline__ short bfr(float f) {       // fp32->bf16 RNE
    unsigned u = __float_as_uint(f);
    return (short)((u + 0x7FFFu + ((u >> 16) & 1u)) >> 16);
}
__device__ __forceinline__ float bf2f(short s) {
    return __uint_as_float(((unsigned)(unsigned short)s) << 16);
}

__device__ __forceinline__ float tmin16(f32x16 d) {   // tree min of 16
    float a0 = fminf(d[0], d[1]),   a1 = fminf(d[2], d[3]);
    float a2 = fminf(d[4], d[5]),   a3 = fminf(d[6], d[7]);
    float a4 = fminf(d[8], d[9]),   a5 = fminf(d[10], d[11]);
    float a6 = fminf(d[12], d[13]), a7 = fminf(d[14], d[15]);
    float b0 = fminf(a0, a1), b1 = fminf(a2, a3);
    float b2 = fminf(a4, a5), b3 = fminf(a6, a7);
    return fminf(fminf(b0, b1), fminf(b2, b3));
}

// grid = (GXB, GYB, 2*NB) = (32, 16, 8) = 4096 blocks, 4 waves each.
// Wave owns 64 x (2 B-frags); block stages YTILE y as A-frags in LDS.
__global__ void __launch_bounds__(TPB) nnmin_mfma(
        const float* __restrict__ T, const float* __restrict__ P,
        unsigned* __restrict__ keys)
{
    __shared__ v4f sA[NTILES * 64];   // A-fragments, 16 KB

    const int z   = blockIdx.z;
    const int dir = z >> 2;
    const int b   = z & 3;
    const float* Xb = (dir ? P : T) + (size_t)b * NPTS * 3;
    const float* Yb = (dir ? T : P) + (size_t)b * NPTS * 3;
    const int t     = threadIdx.x;
    const int l     = t & 63;          // lane
    const int w     = t >> 6;          // wave id (0..3)
    const int ybase = blockIdx.y * YTILE;
    const int xw    = blockIdx.x * XBLK + w * 64;   // wave's 64 x

    // ---- stage A-fragments: 2 y-points per thread, 2 LDS entries each ----
    for (int p = t; p < YTILE; p += TPB) {
        const float* yp = Yb + (size_t)(ybase + p) * 3;
        float y0 = yp[0], y1 = yp[1], y2 = yp[2];
        short yh0 = bfr(y0); short yl0 = bfr(y0 - bf2f(yh0));
        short yh1 = bfr(y1); short yl1 = bfr(y1 - bf2f(yh1));
        short yh2 = bfr(y2); short yl2 = bfr(y2 - bf2f(yh2));
        float hy  = 0.5f * (y0 * y0 + y1 * y1 + y2 * y2);
        short hyh = bfr(hy); short hyl = bfr(hy - bf2f(hyh));
        int tile = p >> 5, m = p & 31;
        union { short s[8]; v4f v; } e0, e1;
        e0.s[0] = yh0; e0.s[1] = yl0; e0.s[2] = yh0; e0.s[3] = yh1;
        e0.s[4] = yl1; e0.s[5] = yh1; e0.s[6] = yh2; e0.s[7] = yl2;
        e1.s[0] = yh2; e1.s[1] = hyh; e1.s[2] = hyl; e1.s[3] = 0;
        e1.s[4] = 0;   e1.s[5] = 0;   e1.s[6] = 0;   e1.s[7] = 0;
        sA[tile * 64 + m]      = e0.v;   // lanes <32 read k=0..7
        sA[tile * 64 + 32 + m] = e1.v;   // lanes >=32 read k=8..15
    }

    // ---- build the wave's two B-fragments (x side), register-resident ----
    const int   kh  = l >> 5;          // which K-half this lane supplies
    const short ONE = 0x3F80;          // bf16(1.0)
    bf16x8 B0, B1;
    {
        int n0 = xw + (l & 31);
#pragma unroll
        for (int f = 0; f < 2; ++f) {
            const float* xp = Xb + (size_t)(n0 + f * 32) * 3;
            float nx = -xp[0], ny = -xp[1], nz = -xp[2];
            short h0 = bfr(nx); short lo0 = bfr(nx - bf2f(h0));
            short h1 = bfr(ny); short lo1 = bfr(ny - bf2f(h1));
            short h2 = bfr(nz); short lo2 = bfr(nz - bf2f(h2));
            union { short s[8]; bf16x8 v; } e;
            if (kh == 0) {
                e.s[0] = h0; e.s[1] = h0; e.s[2] = lo0; e.s[3] = h1;
                e.s[4] = h1; e.s[5] = lo1; e.s[6] = h2; e.s[7] = h2;
            } else {
                e.s[0] = lo2; e.s[1] = ONE; e.s[2] = ONE; e.s[3] = 0;
                e.s[4] = 0;   e.s[5] = 0;   e.s[6] = 0;   e.s[7] = 0;
            }
            if (f == 0) B0 = e.v; else B1 = e.v;
        }
    }
    __syncthreads();

    // ---- main loop: 1 ds_read_b128 + 2 MFMA + 32 v_min per tile ----
    f32x16 zero = {0.f};               // loop-invariant C input
    float rm0 = 3.0e38f, rm1 = 3.0e38f;
#pragma unroll 2
    for (int tl = 0; tl < NTILES; ++tl) {
        v4f a4 = sA[tl * 64 + l];
        bf16x8 A = *(bf16x8*)&a4;
        f32x16 d0 = __builtin_amdgcn_mfma_f32_32x32x16_bf16(A, B0, zero, 0, 0, 0);
        f32x16 d1 = __builtin_amdgcn_mfma_f32_32x32x16_bf16(A, B1, zero, 0, 0, 0);
        rm0 = fminf(rm0, tmin16(d0));
        rm1 = fminf(rm1, tmin16(d1));
    }

    // lane l and l^32 hold the two row-halves of the same x column
    rm0 = fminf(rm0, __shfl_xor(rm0, 32, 64));
    rm1 = fminf(rm1, __shfl_xor(rm1, 32, 64));

    unsigned* o = keys + (size_t)dir * TOTPTS + (size_t)b * NPTS;
    if (l < 32) {
        unsigned b0 = __float_as_uint(rm0);
        unsigned b1 = __float_as_uint(rm1);
        atomicMin(&o[xw + l],
                  b0 ^ ((b0 & 0x80000000u) ? 0xFFFFFFFFu : 0x80000000u));
        atomicMin(&o[xw + 32 + l],
                  b1 ^ ((b1 & 0x80000000u) ? 0xFFFFFFFFu : 0x80000000u));
    }
}

// Decode key, add hx, sqrt; write mins_seeds; per-wave partial sums.
__global__ void __launch_bounds__(TPB) finalize_kernel(
        const unsigned* __restrict__ keys,
        const float* __restrict__ T, const float* __restrict__ P,
        float* __restrict__ out, float* __restrict__ partials)
{
    int i   = blockIdx.x * TPB + threadIdx.x;   // 0 .. 2*TOTPTS-1
    int dir = (i >= TOTPTS) ? 1 : 0;            // uniform per block
    int idx = i - dir * TOTPTS;
    int b   = idx >> 13;
    int x   = idx & (NPTS - 1);

    unsigned k  = keys[i];
    unsigned bb = (k & 0x80000000u) ? (k ^ 0x80000000u) : ~k;
    float m = __uint_as_float(bb);

    const float* xp = (dir ? P : T) + ((size_t)b * NPTS + x) * 3;
    float a0 = xp[0], a1 = xp[1], a2 = xp[2];
    float hx = 0.5f * (a0 * a0 + a1 * a1 + a2 * a2);
    float d  = sqrtf(fmaxf(2.0f * (hx + m), 0.0f));
    if (dir) out[1 + idx] = d;                  // mins_seeds

#pragma unroll
    for (int off = 32; off > 0; off >>= 1)
        d += __shfl_down(d, off, 64);
    if ((threadIdx.x & 63) == 0) partials[i >> 6] = d;
}

__global__ void scalar_kernel(const float* __restrict__ partials,
                              float* __restrict__ out) {
    int t = threadIdx.x;                        // 64 threads
    float s = 0.0f;
#pragma unroll
    for (int k = 0; k < NPARTIAL / 64; ++k)
        s += partials[t * (NPARTIAL / 64) + k];
#pragma unroll
    for (int off = 32; off > 0; off >>= 1)
        s += __shfl_down(s, off, 64);
    if (t == 0) out[0] = s * (1.0f / (float)TOTPTS);
}

extern "C" void kernel_launch(void* const* d_in, const int* in_sizes, int n_in,
                              void* d_out, int out_size, void* d_ws, size_t ws_size,
                              hipStream_t stream) {
    const float* truep = (const float*)d_in[0];   // [4, 8192, 3] fp32
    const float* predp = (const float*)d_in[1];   // [4, 8192, 3] fp32
    float* out = (float*)d_out;                   // [1 + 32768] fp32

    unsigned* keys     = (unsigned*)d_ws;                 // 2*TOTPTS u32
    float*    partials = (float*)(keys + 2 * TOTPTS);     // 1024 floats

    // 0xFFFFFFFF = max flip-key: valid floor for atomicMin. 256 KB.
    hipMemsetAsync(keys, 0xFF, (size_t)2 * TOTPTS * 4, stream);

    dim3 grid(GXB, GYB, 2 * NB);                  // (32, 16, 8) = 4096 blocks
    nnmin_mfma<<<grid, TPB, 0, stream>>>(truep, predp, keys);

    finalize_kernel<<<(2 * TOTPTS) / TPB, TPB, 0, stream>>>(
        keys, truep, predp, out, partials);
    scalar_kernel<<<1, 64, 0, stream>>>(partials, out);
}